// Round 1
// baseline (642.237 us; speedup 1.0000x reference)
//
#include <hip/hip_runtime.h>
#include <math.h>

// Problem constants: inputs [16,256,64,64] f32 NCHW, codebook [1024,256] f32.
// Points N = 16*64*64 = 65536, D = 256, K = 1024.
// d_out (float32, concatenated): z_out [16,256,64,64] | loss | perplexity | idx [65536,1]
#define NPTS   65536
#define DDIM   256
#define KCODES 1024
#define HWSZ   4096          // 64*64
#define ZELEMS 16777216      // 16*256*64*64
#define CHW    1048576       // 256*4096, per-batch stride

// ws layout (bytes):
//   [0,     4096)  counts, 1024 x u32   (zeroed each call)
//   [4096,  8192)  loss partials, 256 x f32 region (zeroed each call)
//   [8192, 12288)  ww = ||w_k||^2, 1024 x f32

// ---------------------------------------------------------------- K0: ||w||^2
__global__ __launch_bounds__(256) void ww_kernel(const float* __restrict__ cb,
                                                 float* __restrict__ ww) {
    int k = blockIdx.x * 256 + threadIdx.x;          // 1024 threads total
    const float4* row = (const float4*)(cb + (size_t)k * DDIM);
    float s = 0.f;
#pragma unroll 8
    for (int d4 = 0; d4 < DDIM / 4; ++d4) {
        float4 v = row[d4];
        s += v.x * v.x + v.y * v.y + v.z * v.z + v.w * v.w;
    }
    ww[k] = s;
}

// ------------------------------------------------------- K1: distances+argmin
// One block per 64-point tile (points are contiguous hw within one batch).
// LDS: x tile stored d-major xs[d][p], 256*64 f32 = 64 KB.
// Thread (i,j): i = tid&15 -> 4 points (4i..4i+3), j = tid>>4 -> 8 codes per
// 128-code k-tile (k = kt*128 + 8j + c). acc[4][8] in registers.
__global__ __launch_bounds__(256) void argmin_kernel(
        const float* __restrict__ in, const float* __restrict__ cb,
        const float* __restrict__ ww, float* __restrict__ idx_out,
        unsigned int* __restrict__ counts) {
    __shared__ float xs[DDIM * 64];                  // 64 KB
    const int tid = threadIdx.x;
    const int n0  = blockIdx.x * 64;
    const int b   = n0 >> 12;                        // /4096
    const int hw0 = n0 & 4095;
    const float* xin = in + (size_t)b * CHW + hw0;

    {   // stage x tile, coalesced 64-wide rows
        const int lane = tid & 63, w = tid >> 6;
        for (int d = w; d < DDIM; d += 4)
            xs[d * 64 + lane] = xin[(size_t)d * HWSZ + lane];
    }
    __syncthreads();

    const int i = tid & 15, j = tid >> 4;
    float best[4];
    int   bidx[4];
#pragma unroll
    for (int p = 0; p < 4; ++p) { best[p] = 3.4e38f; bidx[p] = 0; }

    for (int kt = 0; kt < KCODES / 128; ++kt) {
        const int kbase = kt * 128 + 8 * j;
        float acc[4][8];
#pragma unroll
        for (int p = 0; p < 4; ++p)
#pragma unroll
            for (int c = 0; c < 8; ++c) acc[p][c] = 0.f;

        for (int d = 0; d < DDIM; d += 4) {
            float xv[4][4];                          // [r][p]
#pragma unroll
            for (int r = 0; r < 4; ++r) {
                float4 t4 = *(const float4*)&xs[(d + r) * 64 + 4 * i];
                xv[r][0] = t4.x; xv[r][1] = t4.y; xv[r][2] = t4.z; xv[r][3] = t4.w;
            }
#pragma unroll
            for (int c = 0; c < 8; ++c) {
                float4 w4 = *(const float4*)(cb + (size_t)(kbase + c) * DDIM + d);
                float wv[4] = {w4.x, w4.y, w4.z, w4.w};
#pragma unroll
                for (int r = 0; r < 4; ++r)
#pragma unroll
                    for (int p = 0; p < 4; ++p)
                        acc[p][c] += xv[r][p] * wv[r];
            }
        }
        // fold tile into running argmin (k ascending within thread: first-min kept)
#pragma unroll
        for (int c = 0; c < 8; ++c) {
            const int k = kbase + c;
            const float wwv = ww[k];
#pragma unroll
            for (int p = 0; p < 4; ++p) {
                float s = wwv - 2.f * acc[p][c];     // dist minus const ||x||^2
                if (s < best[p]) { best[p] = s; bidx[p] = k; }
            }
        }
    }

    // cross-thread reduce: 16 candidates per point, lexicographic (s, k)
    __syncthreads();
    float* cs = xs;                                  // [64][16] f32
    int*   ck = (int*)(xs + 1024);                   // [64][16] i32
#pragma unroll
    for (int p = 0; p < 4; ++p) {
        const int pg = 4 * i + p;
        cs[pg * 16 + j] = best[p];
        ck[pg * 16 + j] = bidx[p];
    }
    __syncthreads();
    if (tid < 64) {
        float bs = cs[tid * 16];
        int   bk = ck[tid * 16];
        for (int jj = 1; jj < 16; ++jj) {
            float s = cs[tid * 16 + jj];
            int   k = ck[tid * 16 + jj];
            if (s < bs || (s == bs && k < bk)) { bs = s; bk = k; }
        }
        idx_out[n0 + tid] = (float)bk;
        atomicAdd(&counts[bk], 1u);
    }
}

// ----------------------------------------------- K2: gather + z_out + loss
__global__ __launch_bounds__(256) void gather_kernel(
        const float* __restrict__ in, const float* __restrict__ cb,
        const float* __restrict__ idx_f, float* __restrict__ zout,
        float* __restrict__ partials) {
    const int tid = threadIdx.x;
    const int n   = blockIdx.x * 256 + tid;
    const int b   = n >> 12, hw = n & 4095;
    const int r   = (int)idx_f[n];
    const float* row = cb + (size_t)r * DDIM;
    const float* xp  = in   + (size_t)b * CHW + hw;
    float*       zp  = zout + (size_t)b * CHW + hw;
    float sum = 0.f;
#pragma unroll 4
    for (int c = 0; c < DDIM; ++c) {
        float v = row[c];
        float x = xp[(size_t)c * HWSZ];
        zp[(size_t)c * HWSZ] = v;
        float d = v - x;
        sum += d * d;
    }
#pragma unroll
    for (int o = 32; o; o >>= 1) sum += __shfl_down(sum, o, 64);
    __shared__ float ps[4];
    if ((tid & 63) == 0) ps[tid >> 6] = sum;
    __syncthreads();
    if (tid == 0) partials[blockIdx.x] = ps[0] + ps[1] + ps[2] + ps[3];
}

// ------------------------------------------------------- K3: loss + perplexity
__global__ __launch_bounds__(256) void final_kernel(
        const float* __restrict__ partials, const unsigned int* __restrict__ counts,
        float* __restrict__ out_loss, float* __restrict__ out_perp) {
    const int tid = threadIdx.x;
    float s = partials[tid];                         // 256 partials
    float e = 0.f;
#pragma unroll
    for (int q = 0; q < 4; ++q) {
        float p = (float)counts[tid * 4 + q] * (1.f / 65536.f);
        e += p * logf(p + 1e-10f);
    }
#pragma unroll
    for (int o = 32; o; o >>= 1) {
        s += __shfl_down(s, o, 64);
        e += __shfl_down(e, o, 64);
    }
    __shared__ float ss[4], es[4];
    if ((tid & 63) == 0) { ss[tid >> 6] = s; es[tid >> 6] = e; }
    __syncthreads();
    if (tid == 0) {
        float S = ss[0] + ss[1] + ss[2] + ss[3];
        float E = es[0] + es[1] + es[2] + es[3];
        *out_loss = 0.25f * (S / (float)ZELEMS);     // beta * mean((zq-x)^2)
        *out_perp = expf(-E);
    }
}

extern "C" void kernel_launch(void* const* d_in, const int* in_sizes, int n_in,
                              void* d_out, int out_size, void* d_ws, size_t ws_size,
                              hipStream_t stream) {
    const float* in = (const float*)d_in[0];
    const float* cb = (const float*)d_in[1];
    float* out   = (float*)d_out;
    float* zout  = out;
    float* loss  = out + ZELEMS;
    float* perp  = out + ZELEMS + 1;
    float* idxf  = out + ZELEMS + 2;

    unsigned int* counts   = (unsigned int*)d_ws;
    float*        partials = (float*)((char*)d_ws + 4096);
    float*        ww       = (float*)((char*)d_ws + 8192);

    hipMemsetAsync(d_ws, 0, 8192, stream);           // counts + partials
    ww_kernel    <<<KCODES / 256, 256, 0, stream>>>(cb, ww);
    argmin_kernel<<<NPTS / 64,    256, 0, stream>>>(in, cb, ww, idxf, counts);
    gather_kernel<<<NPTS / 256,   256, 0, stream>>>(in, cb, idxf, zout, partials);
    final_kernel <<<1,            256, 0, stream>>>(partials, counts, loss, perp);
}

// Round 2
// 292.288 us; speedup vs baseline: 2.1973x; 2.1973x over previous
//
#include <hip/hip_runtime.h>
#include <math.h>

// VQ-VAE forward. inputs [16,256,64,64] f32 NCHW, codebook [1024,256] f32.
// N = 65536 points, D = 256, K = 1024.
// d_out f32: z_out [16,256,64,64] | loss | perplexity | idx [65536,1]
#define NPTS   65536
#define DDIM   256
#define KCODES 1024
#define HWSZ   4096
#define ZELEMS 16777216
#define CHW    1048576

// bf16-split GEMM: contraction C=1024 = [xhi(256)|xhi|xlo|xlo] . [whi|wlo|whi|wlo]
// Xs tiled [512 mt][16 kc][128 row][32 col] bf16  (64 MiB) -> lives in z_out region
// Ws tiled [8 ct][16 kc][128 row][32 col] bf16    (1 MiB)  -> in d_ws
// ws layout: counts u32[1024] @0 | ww f32[1024] @4096 | partials f32[256] @8192 | Ws @16384

typedef __attribute__((ext_vector_type(8))) short s16x8;
typedef __attribute__((ext_vector_type(4))) float f32x4;

__device__ __forceinline__ void bf16split(float x, unsigned short& h, unsigned short& l) {
    unsigned u  = __float_as_uint(x);
    unsigned hu = (u + 0x8000u) & 0xFFFF0000u;          // RN-half-up to bf16
    h = (unsigned short)(hu >> 16);
    float r = x - __uint_as_float(hu);                   // exact residual
    l = (unsigned short)((__float_as_uint(r) + 0x8000u) >> 16);
}

// ---------------------------------------------------------------- K0: ||w||^2
__global__ __launch_bounds__(256) void ww_kernel(const float* __restrict__ cb,
                                                 float* __restrict__ ww) {
    int k = blockIdx.x * 256 + threadIdx.x;
    const float4* row = (const float4*)(cb + (size_t)k * DDIM);
    float s = 0.f;
#pragma unroll 8
    for (int d4 = 0; d4 < DDIM / 4; ++d4) {
        float4 v = row[d4];
        s += v.x * v.x + v.y * v.y + v.z * v.z + v.w * v.w;
    }
    ww[k] = s;
}

// --------------------------------------------------- conv_w: codebook -> tiles
// 8192 threads: one per (code, 32-d octet-group). cb row-major read, 64B writes.
__global__ __launch_bounds__(256) void conv_w(const float* __restrict__ cb,
                                              unsigned short* __restrict__ Ws) {
    int gid  = blockIdx.x * 256 + threadIdx.x;           // 0..8191
    int code = gid >> 3, o32 = gid & 7;
    int ct = code >> 7, row = code & 127;
    unsigned short hi[32], lo[32];
#pragma unroll
    for (int j4 = 0; j4 < 8; ++j4) {
        float4 v = *(const float4*)(cb + (size_t)code * DDIM + o32 * 32 + j4 * 4);
        bf16split(v.x, hi[j4*4+0], lo[j4*4+0]);
        bf16split(v.y, hi[j4*4+1], lo[j4*4+1]);
        bf16split(v.z, hi[j4*4+2], lo[j4*4+2]);
        bf16split(v.w, hi[j4*4+3], lo[j4*4+3]);
    }
    size_t bh = ((size_t)(ct * 16 + o32)     * 128 + row) * 32;  // kc = o32   (hi)
    size_t bl = ((size_t)(ct * 16 + o32 + 8) * 128 + row) * 32;  // kc = o32+8 (lo)
#pragma unroll
    for (int c = 0; c < 4; ++c) {
        *(s16x8*)(Ws + bh + c * 8) = *(const s16x8*)&hi[c * 8];
        *(s16x8*)(Ws + bl + c * 8) = *(const s16x8*)&lo[c * 8];
    }
}

// --------------------------------------------- conv_x: NCHW f32 -> tiled bf16
// grid 4096: block = (mt, dc) handles 32 d x 128 hw; LDS transpose.
__global__ __launch_bounds__(256) void conv_x(const float* __restrict__ in,
                                              unsigned short* __restrict__ Xs) {
    __shared__ float xt[32 * 128];                       // 16 KB
    const int tid = threadIdx.x;
    const int mt = blockIdx.x >> 3, dc = blockIdx.x & 7;
    const int b = mt >> 5, hw0 = (mt & 31) << 7, d0 = dc * 32;
    const float* src = in + (size_t)b * CHW + (size_t)d0 * HWSZ + hw0;
#pragma unroll
    for (int r = 0; r < 16; ++r) {
        int e = r * 256 + tid, dd = e >> 7, i = e & 127;
        xt[dd * 128 + i] = src[(size_t)dd * HWSZ + i];
    }
    __syncthreads();
#pragma unroll
    for (int half = 0; half < 2; ++half) {
        int g = half * 256 + tid;                        // 0..511 granules
        int row = g >> 2, o = g & 3;                     // row: point, o: 8-col octet
        unsigned short hi[8], lo[8];
#pragma unroll
        for (int j = 0; j < 8; ++j)
            bf16split(xt[(o * 8 + j) * 128 + row], hi[j], lo[j]);
        size_t bh = ((size_t)(mt * 16 + dc)     * 128 + row) * 32 + o * 8;
        size_t bl = ((size_t)(mt * 16 + dc + 8) * 128 + row) * 32 + o * 8;
        *(s16x8*)(Xs + bh) = *(const s16x8*)hi;
        *(s16x8*)(Xs + bl) = *(const s16x8*)lo;
    }
}

// --------------------------------------- gemm_argmin: MFMA distances + argmin
// 512 blocks (one per 128-point tile) x 256 threads (4 waves, 2x2).
// Per code-tile ct (8 of them): contract C=1024 (32 k-steps of BK=32), fold argmin.
__global__ __launch_bounds__(256) void gemm_argmin(
        const unsigned short* __restrict__ Xs, const unsigned short* __restrict__ Ws,
        const float* __restrict__ ww, float* __restrict__ idx_out,
        unsigned int* __restrict__ counts) {
    __shared__ unsigned short lds[2][2][4096];           // [buf][A/B][128*32] 32 KB
    const int tid = threadIdx.x, lane = tid & 63, w = tid >> 6;
    const int wm = w >> 1, wn = w & 1;
    const int col = lane & 15, kb = lane >> 4;
    const int mt = blockIdx.x;

    f32x4 acc[4][4] = {};
    float best[16];
    int   bidx[16];
#pragma unroll
    for (int i = 0; i < 16; ++i) { best[i] = 3.4e38f; bidx[i] = 0; }

    auto stage = [&](int gs, int buf) {
        const int s = gs & 31, ct = gs >> 5;
        const int kA = (s & 7) | ((s >> 4) << 3);        // hi,hi,lo,lo
        const int kW = (s & 7) | (((s >> 3) & 1) << 3);  // hi,lo,hi,lo
        const unsigned short* ga = Xs + (size_t)(mt * 16 + kA) * 4096 + w * 1024 + lane * 8;
        const unsigned short* gb = Ws + (size_t)(ct * 16 + kW) * 4096 + w * 1024 + lane * 8;
#pragma unroll
        for (int c = 0; c < 2; ++c) {
            __builtin_amdgcn_global_load_lds(
                (const __attribute__((address_space(1))) unsigned*)(ga + c * 512),
                (__attribute__((address_space(3))) unsigned*)&lds[buf][0][w * 1024 + c * 512],
                16, 0, 0);
            __builtin_amdgcn_global_load_lds(
                (const __attribute__((address_space(1))) unsigned*)(gb + c * 512),
                (__attribute__((address_space(3))) unsigned*)&lds[buf][1][w * 1024 + c * 512],
                16, 0, 0);
        }
    };

    int cur = 0;
    stage(0, 0);
    __syncthreads();

    for (int gs = 0; gs < 256; ++gs) {
        if (gs + 1 < 256) stage(gs + 1, cur ^ 1);

        s16x8 af[4], bf[4];
#pragma unroll
        for (int mf = 0; mf < 4; ++mf)
            af[mf] = *(const s16x8*)&lds[cur][0][(wm * 64 + mf * 16 + col) * 32 + kb * 8];
#pragma unroll
        for (int nf = 0; nf < 4; ++nf)
            bf[nf] = *(const s16x8*)&lds[cur][1][(wn * 64 + nf * 16 + col) * 32 + kb * 8];
#pragma unroll
        for (int mf = 0; mf < 4; ++mf)
#pragma unroll
            for (int nf = 0; nf < 4; ++nf)
                acc[mf][nf] = __builtin_amdgcn_mfma_f32_16x16x32_bf16(
                    af[mf], bf[nf], acc[mf][nf], 0, 0, 0);

        if ((gs & 31) == 31) {                           // code-tile done: fold argmin
            const int ct = gs >> 5;
#pragma unroll
            for (int nf = 0; nf < 4; ++nf) {
                const int k = ct * 128 + wn * 64 + nf * 16 + col;
                const float wwv = ww[k];
#pragma unroll
                for (int mf = 0; mf < 4; ++mf)
#pragma unroll
                    for (int r = 0; r < 4; ++r) {
                        float sd = wwv - 2.f * acc[mf][nf][r];
                        const int i = mf * 4 + r;
                        if (sd < best[i]) { best[i] = sd; bidx[i] = k; }
                    }
            }
#pragma unroll
            for (int mf = 0; mf < 4; ++mf)
#pragma unroll
                for (int nf = 0; nf < 4; ++nf)
                    acc[mf][nf] = (f32x4){0.f, 0.f, 0.f, 0.f};
        }
        __syncthreads();
        cur ^= 1;
    }

    // cross-lane (16 cols) butterfly, lexicographic (s, k)
#pragma unroll
    for (int off = 1; off < 16; off <<= 1) {
#pragma unroll
        for (int i = 0; i < 16; ++i) {
            float os = __shfl_xor(best[i], off, 64);
            int   ok = __shfl_xor(bidx[i], off, 64);
            if (os < best[i] || (os == best[i] && ok < bidx[i])) { best[i] = os; bidx[i] = ok; }
        }
    }
    __syncthreads();                                     // lds free for reuse
    float* rs = (float*)&lds[0][0][0];                   // [128][2]
    int*   rk = (int*)(rs + 256);
    const int g = lane >> 4;
    if (col == 0) {
#pragma unroll
        for (int i = 0; i < 16; ++i) {
            int row = wm * 64 + (i >> 2) * 16 + g * 4 + (i & 3);
            rs[row * 2 + wn] = best[i];
            rk[row * 2 + wn] = bidx[i];
        }
    }
    __syncthreads();
    if (tid < 128) {
        float s0 = rs[tid * 2], s1 = rs[tid * 2 + 1];
        int   k0 = rk[tid * 2], k1 = rk[tid * 2 + 1];
        int   k  = (s1 < s0 || (s1 == s0 && k1 < k0)) ? k1 : k0;
        idx_out[mt * 128 + tid] = (float)k;
        atomicAdd(&counts[k], 1u);
    }
}

// ----------------------------------------------- gather + z_out + loss
__global__ __launch_bounds__(256) void gather_kernel(
        const float* __restrict__ in, const float* __restrict__ cb,
        const float* __restrict__ idx_f, float* __restrict__ zout,
        float* __restrict__ partials) {
    const int tid = threadIdx.x;
    const int n   = blockIdx.x * 256 + tid;
    const int b   = n >> 12, hw = n & 4095;
    const int r   = (int)idx_f[n];
    const float* row = cb + (size_t)r * DDIM;
    const float* xp  = in   + (size_t)b * CHW + hw;
    float*       zp  = zout + (size_t)b * CHW + hw;
    float sum = 0.f;
#pragma unroll 4
    for (int c = 0; c < DDIM; ++c) {
        float v = row[c];
        float x = xp[(size_t)c * HWSZ];
        zp[(size_t)c * HWSZ] = v;
        float d = v - x;
        sum += d * d;
    }
#pragma unroll
    for (int o = 32; o; o >>= 1) sum += __shfl_down(sum, o, 64);
    __shared__ float ps[4];
    if ((tid & 63) == 0) ps[tid >> 6] = sum;
    __syncthreads();
    if (tid == 0) partials[blockIdx.x] = ps[0] + ps[1] + ps[2] + ps[3];
}

// ------------------------------------------------------- loss + perplexity
__global__ __launch_bounds__(256) void final_kernel(
        const float* __restrict__ partials, const unsigned int* __restrict__ counts,
        float* __restrict__ out_loss, float* __restrict__ out_perp) {
    const int tid = threadIdx.x;
    float s = partials[tid];
    float e = 0.f;
#pragma unroll
    for (int q = 0; q < 4; ++q) {
        float p = (float)counts[tid * 4 + q] * (1.f / 65536.f);
        e += p * logf(p + 1e-10f);
    }
#pragma unroll
    for (int o = 32; o; o >>= 1) {
        s += __shfl_down(s, o, 64);
        e += __shfl_down(e, o, 64);
    }
    __shared__ float ss[4], es[4];
    if ((tid & 63) == 0) { ss[tid >> 6] = s; es[tid >> 6] = e; }
    __syncthreads();
    if (tid == 0) {
        float S = ss[0] + ss[1] + ss[2] + ss[3];
        float E = es[0] + es[1] + es[2] + es[3];
        *out_loss = 0.25f * (S / (float)ZELEMS);
        *out_perp = expf(-E);
    }
}

extern "C" void kernel_launch(void* const* d_in, const int* in_sizes, int n_in,
                              void* d_out, int out_size, void* d_ws, size_t ws_size,
                              hipStream_t stream) {
    (void)in_sizes; (void)n_in; (void)out_size; (void)ws_size;
    const float* in = (const float*)d_in[0];
    const float* cb = (const float*)d_in[1];
    float* out  = (float*)d_out;
    float* zout = out;
    float* loss = out + ZELEMS;
    float* perp = out + ZELEMS + 1;
    float* idxf = out + ZELEMS + 2;

    unsigned int*   counts   = (unsigned int*)d_ws;
    float*          ww       = (float*)((char*)d_ws + 4096);
    float*          partials = (float*)((char*)d_ws + 8192);
    unsigned short* Ws       = (unsigned short*)((char*)d_ws + 16384);
    unsigned short* Xs       = (unsigned short*)zout;    // scratch; overwritten by gather

    hipMemsetAsync(counts, 0, 4096, stream);
    ww_kernel  <<<KCODES / 256, 256, 0, stream>>>(cb, ww);
    conv_w     <<<32,           256, 0, stream>>>(cb, Ws);
    conv_x     <<<4096,         256, 0, stream>>>(in, Xs);
    gemm_argmin<<<512,          256, 0, stream>>>(Xs, Ws, ww, idxf, counts);
    gather_kernel<<<NPTS / 256, 256, 0, stream>>>(in, cb, idxf, zout, partials);
    final_kernel <<<1,          256, 0, stream>>>(partials, counts, loss, perp);
}

// Round 3
// 236.718 us; speedup vs baseline: 2.7131x; 1.2348x over previous
//
#include <hip/hip_runtime.h>
#include <math.h>

// VQ-VAE forward. inputs [16,256,64,64] f32 NCHW, codebook [1024,256] f32.
// N = 65536 points, D = 256, K = 1024.
// d_out f32: z_out [16,256,64,64] | loss | perplexity | idx [65536,1]
#define NPTS   65536
#define DDIM   256
#define KCODES 1024
#define HWSZ   4096
#define ZELEMS 16777216
#define CHW    1048576

// bf16-split GEMM, contraction C=1024 = [xhi|xhi|xlo|xlo].[whi|wlo|whi|wlo].
// Tiles are FRAGMENT-ORDERED in global memory (we own the packer):
//   tile (mt|ct, kc) = 128 rows x 32 k, stored as [subtile=row>>4][lane][8elem]
//   where lane = (row&15) | ((k>>3)<<4), elem = k&7.
// => global_load_lds stages linearly, ds_read_b128 is lane*16B contiguous
//    (zero bank conflicts), MFMA fragments need no in-kernel shuffling.
// Xs [512 mt][16 kc][4096] bf16 (64 MiB) lives in z_out region (scratch).
// Ws [8 ct][16 kc][4096] bf16 (1 MiB) in d_ws.
// ws layout: counts u32[1024] @0 | ww f32[1024] @4096 | partials @8192 | Ws @16384

typedef __attribute__((ext_vector_type(8))) short s16x8;
typedef __attribute__((ext_vector_type(4))) float f32x4;

__device__ __forceinline__ void bf16split(float x, unsigned short& h, unsigned short& l) {
    unsigned u  = __float_as_uint(x);
    unsigned hu = (u + 0x8000u) & 0xFFFF0000u;          // RN-ish to bf16
    h = (unsigned short)(hu >> 16);
    float r = x - __uint_as_float(hu);                   // exact residual
    l = (unsigned short)((__float_as_uint(r) + 0x8000u) >> 16);
}

// ------------------------------------------- conv_w: codebook -> tiles + ||w||^2
__global__ __launch_bounds__(256) void conv_w(const float* __restrict__ cb,
                                              unsigned short* __restrict__ Ws,
                                              float* __restrict__ ww) {
    int gid  = blockIdx.x * 256 + threadIdx.x;           // 0..8191
    int code = gid >> 3, o32 = gid & 7;                  // o32: 32-dim chunk
    int ct = code >> 7, row = code & 127;
    unsigned short hi[32], lo[32];
    float ss = 0.f;
#pragma unroll
    for (int j4 = 0; j4 < 8; ++j4) {
        float4 v = *(const float4*)(cb + (size_t)code * DDIM + o32 * 32 + j4 * 4);
        ss += v.x * v.x + v.y * v.y + v.z * v.z + v.w * v.w;
        bf16split(v.x, hi[j4*4+0], lo[j4*4+0]);
        bf16split(v.y, hi[j4*4+1], lo[j4*4+1]);
        bf16split(v.z, hi[j4*4+2], lo[j4*4+2]);
        bf16split(v.w, hi[j4*4+3], lo[j4*4+3]);
    }
    ss += __shfl_down(ss, 4, 8);
    ss += __shfl_down(ss, 2, 8);
    ss += __shfl_down(ss, 1, 8);
    if (o32 == 0) ww[code] = ss;
    size_t bh = (size_t)(ct * 16 + o32)     * 4096 + (row >> 4) * 512;
    size_t bl = (size_t)(ct * 16 + o32 + 8) * 4096 + (row >> 4) * 512;
#pragma unroll
    for (int c = 0; c < 4; ++c) {                        // fragment order
        size_t fo = (size_t)(((row & 15) + 16 * c)) * 8;
        *(s16x8*)(Ws + bh + fo) = *(const s16x8*)&hi[c * 8];
        *(s16x8*)(Ws + bl + fo) = *(const s16x8*)&lo[c * 8];
    }
}

// --------------------------------- conv_x: NCHW f32 -> fragment-ordered bf16
__global__ __launch_bounds__(256) void conv_x(const float* __restrict__ in,
                                              unsigned short* __restrict__ Xs) {
    __shared__ float xt[32 * 128];                       // 16 KB
    const int tid = threadIdx.x;
    const int mt = blockIdx.x >> 3, dc = blockIdx.x & 7;
    const int b = mt >> 5, hw0 = (mt & 31) << 7;
    const float* src = in + (size_t)b * CHW + (size_t)(dc * 32) * HWSZ + hw0;
#pragma unroll
    for (int r = 0; r < 16; ++r) {
        int e = r * 256 + tid, dd = e >> 7, i = e & 127;
        xt[dd * 128 + i] = src[(size_t)dd * HWSZ + i];
    }
    __syncthreads();
#pragma unroll
    for (int half = 0; half < 2; ++half) {
        int g = half * 256 + tid;                        // 0..511
        int row = g >> 2, o = g & 3;                     // point row, k-octet
        unsigned short hi[8], lo[8];
#pragma unroll
        for (int j = 0; j < 8; ++j)
            bf16split(xt[(o * 8 + j) * 128 + row], hi[j], lo[j]);
        size_t fo = (size_t)(row >> 4) * 512 + (size_t)((row & 15) + 16 * o) * 8;
        size_t bh = (size_t)(mt * 16 + dc)     * 4096 + fo;
        size_t bl = (size_t)(mt * 16 + dc + 8) * 4096 + fo;
        *(s16x8*)(Xs + bh) = *(const s16x8*)hi;
        *(s16x8*)(Xs + bl) = *(const s16x8*)lo;
    }
}

// --------------------------------------- gemm_argmin: MFMA distances + argmin
// 512 blocks x 256 threads (4 waves 2x2, wave tile 64x64).
// Depth-3 prefetch, 4 LDS buffers, counted vmcnt(8), raw s_barrier.
__global__ __launch_bounds__(256) void gemm_argmin(
        const unsigned short* __restrict__ Xs, const unsigned short* __restrict__ Ws,
        const float* __restrict__ ww, float* __restrict__ idx_out,
        unsigned int* __restrict__ counts) {
    __shared__ unsigned short lds[4][2][4096];           // 64 KiB: [buf][A/B]
    const int tid = threadIdx.x, lane = tid & 63, w = tid >> 6;
    const int wm = w >> 1, wn = w & 1;
    const int col = lane & 15;
    const int mt = blockIdx.x;

    f32x4 acc[4][4] = {};
    float best[16];
    int   bidx[16];
#pragma unroll
    for (int i = 0; i < 16; ++i) { best[i] = 3.4e38f; bidx[i] = 0; }

    const unsigned short* XsB = Xs + (size_t)mt * 65536;

    auto stage = [&](int gs) {
        const int b = gs & 3;
        const int s = gs & 31, ct = gs >> 5;
        const int kA = (s & 7) | ((s >> 4) << 3);        // hi,hi,lo,lo
        const int kW = (s & 7) | (((s >> 3) & 1) << 3);  // hi,lo,hi,lo
        const unsigned short* ga = XsB + kA * 4096 + w * 512 + lane * 8;
        const unsigned short* gb = Ws + (size_t)(ct * 16 + kW) * 4096 + w * 512 + lane * 8;
#pragma unroll
        for (int c = 0; c < 2; ++c) {
            __builtin_amdgcn_global_load_lds(
                (const __attribute__((address_space(1))) unsigned*)(ga + c * 2048),
                (__attribute__((address_space(3))) unsigned*)&lds[b][0][c * 2048 + w * 512],
                16, 0, 0);
            __builtin_amdgcn_global_load_lds(
                (const __attribute__((address_space(1))) unsigned*)(gb + c * 2048),
                (__attribute__((address_space(3))) unsigned*)&lds[b][1][c * 2048 + w * 512],
                16, 0, 0);
        }
    };

    auto compute = [&](int s) {
        const int b = s & 3;
        s16x8 af[4], bfr[4];
#pragma unroll
        for (int mf = 0; mf < 4; ++mf)
            af[mf] = *(const s16x8*)&lds[b][0][(wm * 4 + mf) * 512 + lane * 8];
#pragma unroll
        for (int nf = 0; nf < 4; ++nf)
            bfr[nf] = *(const s16x8*)&lds[b][1][(wn * 4 + nf) * 512 + lane * 8];
#pragma unroll
        for (int mf = 0; mf < 4; ++mf)
#pragma unroll
            for (int nf = 0; nf < 4; ++nf)
                acc[mf][nf] = __builtin_amdgcn_mfma_f32_16x16x32_bf16(
                    af[mf], bfr[nf], acc[mf][nf], 0, 0, 0);
        if ((s & 31) == 31) {                            // code-tile done: fold
            const int ct = s >> 5;
#pragma unroll
            for (int nf = 0; nf < 4; ++nf) {
                const int k = ct * 128 + wn * 64 + nf * 16 + col;
                const float wwv = ww[k];
#pragma unroll
                for (int mf = 0; mf < 4; ++mf)
#pragma unroll
                    for (int r = 0; r < 4; ++r) {
                        float sd = wwv - 2.f * acc[mf][nf][r];
                        const int i = mf * 4 + r;
                        if (sd < best[i]) { best[i] = sd; bidx[i] = k; }
                    }
            }
#pragma unroll
            for (int mf = 0; mf < 4; ++mf)
#pragma unroll
                for (int nf = 0; nf < 4; ++nf)
                    acc[mf][nf] = (f32x4){0.f, 0.f, 0.f, 0.f};
        }
    };

    stage(0); stage(1); stage(2);                        // depth-3 prologue
    for (int s = 0; s < 253; ++s) {
        asm volatile("s_waitcnt vmcnt(8)" ::: "memory"); // stage-s landed (mine)
        __builtin_amdgcn_s_barrier();                    // all waves: stage-s in, s-1 read
        stage(s + 3);                                    // overwrite buf[(s-1)&3]
        compute(s);
    }
    asm volatile("s_waitcnt vmcnt(8)" ::: "memory");
    __builtin_amdgcn_s_barrier();
    compute(253);
    asm volatile("s_waitcnt vmcnt(4)" ::: "memory");
    __builtin_amdgcn_s_barrier();
    compute(254);
    asm volatile("s_waitcnt vmcnt(0)" ::: "memory");
    __builtin_amdgcn_s_barrier();
    compute(255);

    // cross-lane (16 cols) butterfly, lexicographic (s, k)
#pragma unroll
    for (int off = 1; off < 16; off <<= 1) {
#pragma unroll
        for (int i = 0; i < 16; ++i) {
            float os = __shfl_xor(best[i], off, 64);
            int   ok = __shfl_xor(bidx[i], off, 64);
            if (os < best[i] || (os == best[i] && ok < bidx[i])) { best[i] = os; bidx[i] = ok; }
        }
    }
    __syncthreads();
    float* rs = (float*)&lds[0][0][0];                   // [128][2]
    int*   rk = (int*)(rs + 256);
    const int g = lane >> 4;
    if (col == 0) {
#pragma unroll
        for (int i = 0; i < 16; ++i) {
            int row = wm * 64 + (i >> 2) * 16 + g * 4 + (i & 3);
            rs[row * 2 + wn] = best[i];
            rk[row * 2 + wn] = bidx[i];
        }
    }
    __syncthreads();
    if (tid < 128) {
        float s0 = rs[tid * 2], s1 = rs[tid * 2 + 1];
        int   k0 = rk[tid * 2], k1 = rk[tid * 2 + 1];
        int   k  = (s1 < s0 || (s1 == s0 && k1 < k0)) ? k1 : k0;
        idx_out[mt * 128 + tid] = (float)k;
        atomicAdd(&counts[k], 1u);
    }
}

// ----------------------------------------------- gather + z_out + loss
__global__ __launch_bounds__(256) void gather_kernel(
        const float* __restrict__ in, const float* __restrict__ cb,
        const float* __restrict__ idx_f, float* __restrict__ zout,
        float* __restrict__ partials) {
    const int tid = threadIdx.x;
    const int n   = blockIdx.x * 256 + tid;
    const int b   = n >> 12, hw = n & 4095;
    const int r   = (int)idx_f[n];
    const float* row = cb + (size_t)r * DDIM;
    const float* xp  = in   + (size_t)b * CHW + hw;
    float*       zp  = zout + (size_t)b * CHW + hw;
    float sum = 0.f;
#pragma unroll 4
    for (int c = 0; c < DDIM; ++c) {
        float v = row[c];
        float x = xp[(size_t)c * HWSZ];
        zp[(size_t)c * HWSZ] = v;
        float d = v - x;
        sum += d * d;
    }
#pragma unroll
    for (int o = 32; o; o >>= 1) sum += __shfl_down(sum, o, 64);
    __shared__ float ps[4];
    if ((tid & 63) == 0) ps[tid >> 6] = sum;
    __syncthreads();
    if (tid == 0) partials[blockIdx.x] = ps[0] + ps[1] + ps[2] + ps[3];
}

// ------------------------------------------------------- loss + perplexity
__global__ __launch_bounds__(256) void final_kernel(
        const float* __restrict__ partials, const unsigned int* __restrict__ counts,
        float* __restrict__ out_loss, float* __restrict__ out_perp) {
    const int tid = threadIdx.x;
    float s = partials[tid];
    float e = 0.f;
#pragma unroll
    for (int q = 0; q < 4; ++q) {
        float p = (float)counts[tid * 4 + q] * (1.f / 65536.f);
        e += p * logf(p + 1e-10f);
    }
#pragma unroll
    for (int o = 32; o; o >>= 1) {
        s += __shfl_down(s, o, 64);
        e += __shfl_down(e, o, 64);
    }
    __shared__ float ss[4], es[4];
    if ((tid & 63) == 0) { ss[tid >> 6] = s; es[tid >> 6] = e; }
    __syncthreads();
    if (tid == 0) {
        float S = ss[0] + ss[1] + ss[2] + ss[3];
        float E = es[0] + es[1] + es[2] + es[3];
        *out_loss = 0.25f * (S / (float)ZELEMS);
        *out_perp = expf(-E);
    }
}

extern "C" void kernel_launch(void* const* d_in, const int* in_sizes, int n_in,
                              void* d_out, int out_size, void* d_ws, size_t ws_size,
                              hipStream_t stream) {
    (void)in_sizes; (void)n_in; (void)out_size; (void)ws_size;
    const float* in = (const float*)d_in[0];
    const float* cb = (const float*)d_in[1];
    float* out  = (float*)d_out;
    float* zout = out;
    float* loss = out + ZELEMS;
    float* perp = out + ZELEMS + 1;
    float* idxf = out + ZELEMS + 2;

    unsigned int*   counts   = (unsigned int*)d_ws;
    float*          ww       = (float*)((char*)d_ws + 4096);
    float*          partials = (float*)((char*)d_ws + 8192);
    unsigned short* Ws       = (unsigned short*)((char*)d_ws + 16384);
    unsigned short* Xs       = (unsigned short*)zout;    // scratch; overwritten by gather

    hipMemsetAsync(counts, 0, 4096, stream);
    conv_w     <<<32,           256, 0, stream>>>(cb, Ws, ww);
    conv_x     <<<4096,         256, 0, stream>>>(in, Xs);
    gemm_argmin<<<512,          256, 0, stream>>>(Xs, Ws, ww, idxf, counts);
    gather_kernel<<<NPTS / 256, 256, 0, stream>>>(in, cb, idxf, zout, partials);
    final_kernel <<<1,          256, 0, stream>>>(partials, counts, loss, perp);
}